// Round 12
// baseline (265.480 us; speedup 1.0000x reference)
//
#include <hip/hip_runtime.h>
#include <hip/hip_bf16.h>
#include <type_traits>

#define T_STEPS 256
#define BATCH   2048
#define INSZ    65
#define HID     64
#define ROWS    8        // 2 independent 4-row streams -> 256 blocks = 1 block/CU
#define OUTSZ   7
#define NTHREADS 256

// LDS (shorts). Two independent per-stream copies of the round-7 layout:
//  XBA/XBB [0,2048): x A-tiles, M=16 (m = 4*row + tstep_local), K=64 frag-major:
//               element(m,k) at (k>>3)*128 + m*8 + (k&7)
//  HA0/HA1/HB0/HB1: h slots (256 shorts each),
//               element(row,k) at (k>>3)*32 + row*8 + (k&7)
#define XBA  0
#define XBB  1024
#define HA0  2048
#define HA1  2304
#define HB0  2560
#define HB1  2816

typedef __attribute__((ext_vector_type(8))) short bf16x8;  // 8 bf16 = 4 VGPRs
typedef __attribute__((ext_vector_type(4))) short short4v; // 4 bf16 = 2 VGPRs
typedef __attribute__((ext_vector_type(4))) float f32x4;

// f32->bf16 RNE via HIP intrinsic (round-2 post-mortem: no inline-asm cvt).
__device__ __forceinline__ short f2bf(float f) {
    __hip_bfloat16 b = __float2bfloat16(f);
    return (short)__builtin_bit_cast(unsigned short, b);
}
__device__ __forceinline__ float bf2f(short s) {
    union { unsigned u; float f; } v;
    v.u = ((unsigned)(unsigned short)s) << 16;
    return v.f;
}

// Gate pre-activations PRE-SCALED (folded into weights/bias):
//   i,f,o scaled by -log2(e)  -> sigmoid(x) = rcp(1 + exp2(x'))
//   g     scaled by +2log2(e); cell state carried pre-scaled c' = 2log2(e)*c
#define NLOG2E -1.4426950408889634f
#define SGSCL   2.8853900817779268f

__device__ __forceinline__ float sigm2(float a) {
    return __builtin_amdgcn_rcpf(1.0f + __builtin_amdgcn_exp2f(a));
}

// LDS-visibility-only barrier (round-4 win: no vmcnt drain; prefetch global
// loads stay in flight across barriers).
#define BAR() do { \
    asm volatile("s_waitcnt lgkmcnt(0)" ::: "memory"); \
    __builtin_amdgcn_s_barrier(); \
} while (0)

#define IC(n) std::integral_constant<int, n>{}

// 1 block/CU (grid=256): launch_bounds(,1) -> full 512-VGPR budget, no spill
// risk at ~200 VGPR. Residency is grid-limited to 1 wave/SIMD by design; the
// latency overlap that round-10 lacked comes from the DUAL STREAMS (ILP), not
// TLP: while stream A's activation chain stalls, stream B's MFMAs issue.
__global__ __launch_bounds__(NTHREADS, 1)
void lstm_fused(const float* __restrict__ x,    const float* __restrict__ W_ih,
                const float* __restrict__ W_hh, const float* __restrict__ b_ih,
                const float* __restrict__ b_hh, const float* __restrict__ fc_W,
                const float* __restrict__ fc_b, float* __restrict__ out)
{
    __shared__ __align__(16) short Abuf[3072];

    const int tid  = threadIdx.x;
    const int w    = tid >> 6;        // wave 0..3 = hidden-col tile [16w,16w+16)
    const int lane = tid & 63;
    const int quad = lane >> 4;       // batch row (within stream) / tl for staging
    const int col  = lane & 15;
    const int b0   = blockIdx.x * ROWS;   // stream A: b0..b0+3, stream B: b0+4..b0+7

    // zero all 4 h slots (1024 shorts at 2048..3071)
    Abuf[HA0 + tid]       = 0;
    Abuf[HA0 + 256 + tid] = 0;
    Abuf[HA0 + 512 + tid] = 0;
    Abuf[HA0 + 768 + tid] = 0;

    // ---- weight fragments (B layout: n = lane&15, k = quad*8+j), pre-scaled ----
    // kc 0,1: x-part (k 0..63 of W_ih); kc 2,3: h-part (W_hh). k=64 -> acc_bx fold.
    // Shared by both streams (the whole point of packing 2 streams in one wave).
    bf16x8 wfrag[4][4];
    float  wl[4];
    f32x4  bias4[4];
    #pragma unroll
    for (int gt = 0; gt < 4; ++gt) {
        const float sc = (gt == 2) ? SGSCL : NLOG2E;
        const int n = gt * 64 + w * 16 + col;
        #pragma unroll
        for (int kc = 0; kc < 2; ++kc) {
            bf16x8 f;
            #pragma unroll
            for (int j = 0; j < 8; ++j)
                f[j] = f2bf(W_ih[n * INSZ + kc * 32 + quad * 8 + j] * sc);
            wfrag[gt][kc] = f;
        }
        #pragma unroll
        for (int kc = 2; kc < 4; ++kc) {
            bf16x8 f;
            #pragma unroll
            for (int j = 0; j < 8; ++j)
                f[j] = f2bf(W_hh[n * HID + (kc - 2) * 32 + quad * 8 + j] * sc);
            wfrag[gt][kc] = f;
        }
        wl[gt] = W_ih[n * INSZ + 64] * sc;
        const float bv = (b_ih[n] + b_hh[n]) * sc;
        bias4[gt] = (f32x4){bv, bv, bv, bv};
    }

    // h A-frag read: A row m holds h[row m>>2] (replication) -> gate at any reg.
    const int rbase = quad * 32 + (col >> 2) * 8;
    // batched-x A-frag read: A row m = col holds x[row m>>2][t + (m&3)][k]
    const int rbx   = quad * 128 + col * 8;
    const int hwoff = (2 * w + (col >> 3)) * 32 + quad * 8 + (col & 7);  // h write
    // x stage write: thread (w,lane) owns (row w, tl=quad, feats col*4..col*4+3)
    const int xswoff = (col >> 1) * 128 + (4 * w + quad) * 8 + (col & 1) * 4;

    // per-stream global pointers
    const float* xrA = x + (size_t)(b0 + w)        * T_STEPS * INSZ;
    const float* xrB = x + (size_t)(b0 + 4 + w)    * T_STEPS * INSZ;
    const float* xeA = x + (size_t)(b0 + quad)     * T_STEPS * INSZ + 64;
    const float* xeB = x + (size_t)(b0 + 4 + quad) * T_STEPS * INSZ + 64;

    // ---- prologue: stage group 0 for both streams, preload ldA (group 1) ----
    {
        short4v p0, p1;
        #pragma unroll
        for (int j = 0; j < 4; ++j) {
            p0[j] = f2bf(xrA[quad * INSZ + col * 4 + j]);
            p1[j] = f2bf(xrB[quad * INSZ + col * 4 + j]);
        }
        *(short4v*)&Abuf[XBA + xswoff] = p0;
        *(short4v*)&Abuf[XBB + xswoff] = p1;
    }
    float ldAA[4], ldAB[4];
    #pragma unroll
    for (int j = 0; j < 4; ++j) {
        ldAA[j] = xrA[(4 + quad) * INSZ + col * 4 + j];
        ldAB[j] = xrB[(4 + quad) * INSZ + col * 4 + j];
    }
    float fxA[4], fxB[4];
    #pragma unroll
    for (int s = 0; s < 4; ++s) { fxA[s] = xeA[s * INSZ]; fxB[s] = xeB[s * INSZ]; }
    float cA = 0.0f, cB = 0.0f;   // carried pre-scaled: c' = SGSCL * c_true
    f32x4 acc_bxA[4], acc_bxB[4];
    __syncthreads();

    // batched x-MFMA for group 0, both streams
    {
        const bf16x8 x0A = *(const bf16x8*)&Abuf[XBA + rbx];
        const bf16x8 x1A = *(const bf16x8*)&Abuf[XBA + rbx + 512];
        const bf16x8 x0B = *(const bf16x8*)&Abuf[XBB + rbx];
        const bf16x8 x1B = *(const bf16x8*)&Abuf[XBB + rbx + 512];
        #pragma unroll
        for (int gt = 0; gt < 4; ++gt) {
            f32x4 a = __builtin_amdgcn_mfma_f32_16x16x32_bf16(x0A, wfrag[gt][0], bias4[gt], 0, 0, 0);
            a = __builtin_amdgcn_mfma_f32_16x16x32_bf16(x1A, wfrag[gt][1], a, 0, 0, 0);
            f32x4 b = __builtin_amdgcn_mfma_f32_16x16x32_bf16(x0B, wfrag[gt][0], bias4[gt], 0, 0, 0);
            b = __builtin_amdgcn_mfma_f32_16x16x32_bf16(x1B, wfrag[gt][1], b, 0, 0, 0);
            #pragma unroll
            for (int i = 0; i < 4; ++i) {
                a[i] = __builtin_fmaf(wl[gt], fxA[i], a[i]);
                b[i] = __builtin_fmaf(wl[gt], fxB[i], b[i]);
            }
            acc_bxA[gt] = a;
            acc_bxB[gt] = b;
        }
    }
    // no barrier needed: XB next written in s1 (post-BAR(s0)); s0 reads zeroed h.

    // One SUPERSTEP = one LSTM step for BOTH independent streams, one barrier.
    // ds_reads for both streams issue first; 16 MFMAs; the two activation
    // chains are independent -> compiler interleaves them (ILP covers the
    // serial latency that 1-wave/SIMD TLP cannot -- round-10 lesson inverted).
    auto superstep = [&](auto Sc, int HRA, int HWA, int HRB, int HWB, auto&& shadow) {
        constexpr int S = decltype(Sc)::value;
        const bf16x8 a2A = *(const bf16x8*)&Abuf[HRA + rbase];
        const bf16x8 a3A = *(const bf16x8*)&Abuf[HRA + rbase + 128];
        const bf16x8 a2B = *(const bf16x8*)&Abuf[HRB + rbase];
        const bf16x8 a3B = *(const bf16x8*)&Abuf[HRB + rbase + 128];
        f32x4 gA[4], gB[4];
        #pragma unroll
        for (int gt = 0; gt < 4; ++gt) {
            f32x4 a = __builtin_amdgcn_mfma_f32_16x16x32_bf16(a2A, wfrag[gt][2], acc_bxA[gt], 0, 0, 0);
            gA[gt]  = __builtin_amdgcn_mfma_f32_16x16x32_bf16(a3A, wfrag[gt][3], a, 0, 0, 0);
            f32x4 b = __builtin_amdgcn_mfma_f32_16x16x32_bf16(a2B, wfrag[gt][2], acc_bxB[gt], 0, 0, 0);
            gB[gt]  = __builtin_amdgcn_mfma_f32_16x16x32_bf16(a3B, wfrag[gt][3], b, 0, 0, 0);
        }
        // stream A activation (gate value for step S is reg S -- batched-x trick)
        {
            const float gi = sigm2(gA[0][S]);
            const float gf = sigm2(gA[1][S]);
            const float rg = __builtin_amdgcn_rcpf(1.0f + __builtin_amdgcn_exp2f(gA[2][S]));
            const float gg = __builtin_fmaf(rg, -2.0f * SGSCL, SGSCL);
            const float go = sigm2(gA[3][S]);
            cA = __builtin_fmaf(gf, cA, gi * gg);
            const float rc = __builtin_amdgcn_rcpf(1.0f + __builtin_amdgcn_exp2f(cA));
            const float h  = go * __builtin_fmaf(rc, -2.0f, 1.0f);
            Abuf[HWA + hwoff] = f2bf(h);
        }
        // stream B activation (independent chain)
        {
            const float gi = sigm2(gB[0][S]);
            const float gf = sigm2(gB[1][S]);
            const float rg = __builtin_amdgcn_rcpf(1.0f + __builtin_amdgcn_exp2f(gB[2][S]));
            const float gg = __builtin_fmaf(rg, -2.0f * SGSCL, SGSCL);
            const float go = sigm2(gB[3][S]);
            cB = __builtin_fmaf(gf, cB, gi * gg);
            const float rc = __builtin_amdgcn_rcpf(1.0f + __builtin_amdgcn_exp2f(cB));
            const float h  = go * __builtin_fmaf(rc, -2.0f, 1.0f);
            Abuf[HWB + hwoff] = f2bf(h);
        }
        shadow();
        BAR();   // lgkmcnt-only: prefetch vmem stays in flight
    };

    for (int t = 0; t < T_STEPS; t += 4) {
        // group-top global loads for BOTH streams (never drained at a barrier):
        //   ldB*: x feats for group t+8; nf*: k=64 fixups for group t+4
        int tsb = t + 8 + quad; tsb = tsb > 255 ? 255 : tsb;
        float ldBA[4], ldBB[4], nfA[4], nfB[4];
        #pragma unroll
        for (int j = 0; j < 4; ++j) {
            ldBA[j] = xrA[tsb * INSZ + col * 4 + j];
            ldBB[j] = xrB[tsb * INSZ + col * 4 + j];
        }
        #pragma unroll
        for (int s = 0; s < 4; ++s) {
            int tf = t + 4 + s; tf = tf > 255 ? 255 : tf;
            nfA[s] = xeA[tf * INSZ];
            nfB[s] = xeB[tf * INSZ];
        }
        short4v pkA, pkB;
        // s0: cvt next-group feats in the activation shadow
        superstep(IC(0), HA1, HA0, HB1, HB0, [&] {
            #pragma unroll
            for (int j = 0; j < 4; ++j) { pkA[j] = f2bf(ldAA[j]); pkB[j] = f2bf(ldAB[j]); }
        });
        // s1: stage writes (post-BAR(s0): prior XB readers done; reader is s3)
        superstep(IC(1), HA0, HA1, HB0, HB1, [&] {
            *(short4v*)&Abuf[XBA + xswoff] = pkA;
            *(short4v*)&Abuf[XBB + xswoff] = pkB;
        });
        superstep(IC(2), HA1, HA0, HB1, HB0, [&] {});
        // s3: batched x-MFMA rebuild for group t+4, both streams (off-path)
        superstep(IC(3), HA0, HA1, HB0, HB1, [&] {
            const bf16x8 x0A = *(const bf16x8*)&Abuf[XBA + rbx];
            const bf16x8 x1A = *(const bf16x8*)&Abuf[XBA + rbx + 512];
            const bf16x8 x0B = *(const bf16x8*)&Abuf[XBB + rbx];
            const bf16x8 x1B = *(const bf16x8*)&Abuf[XBB + rbx + 512];
            #pragma unroll
            for (int gt = 0; gt < 4; ++gt) {
                f32x4 a = __builtin_amdgcn_mfma_f32_16x16x32_bf16(x0A, wfrag[gt][0], bias4[gt], 0, 0, 0);
                a = __builtin_amdgcn_mfma_f32_16x16x32_bf16(x1A, wfrag[gt][1], a, 0, 0, 0);
                f32x4 b = __builtin_amdgcn_mfma_f32_16x16x32_bf16(x0B, wfrag[gt][0], bias4[gt], 0, 0, 0);
                b = __builtin_amdgcn_mfma_f32_16x16x32_bf16(x1B, wfrag[gt][1], b, 0, 0, 0);
                #pragma unroll
                for (int i = 0; i < 4; ++i) {
                    a[i] = __builtin_fmaf(wl[gt], nfA[i], a[i]);
                    b[i] = __builtin_fmaf(wl[gt], nfB[i], b[i]);
                }
                acc_bxA[gt] = a;
                acc_bxB[gt] = b;
            }
            #pragma unroll
            for (int j = 0; j < 4; ++j) { ldAA[j] = ldBA[j]; ldAB[j] = ldBB[j]; }
        });
    }

    // ---- FC(64->7) + sigmoid; h_255: stream A in HA1, stream B in HB1 ----
    // last superstep ended with BAR(): all h writes visible.
    if (tid < ROWS * OUTSZ) {   // 56 threads
        const int m = tid & 7;                 // 0..7 = batch row within block
        const int o = tid >> 3;                // 0..6
        const int base = (m < 4) ? HA1 : HB1;
        const int mr = m & 3;
        float s = fc_b[o];
        #pragma unroll
        for (int k = 0; k < HID; ++k)
            s += bf2f(Abuf[base + (k >> 3) * 32 + mr * 8 + (k & 7)]) * fc_W[o * HID + k];
        out[(size_t)(b0 + m) * OUTSZ + o] =
            __builtin_amdgcn_rcpf(1.0f + __builtin_amdgcn_exp2f(NLOG2E * s));
    }
}

extern "C" void kernel_launch(void* const* d_in, const int* in_sizes, int n_in,
                              void* d_out, int out_size, void* d_ws, size_t ws_size,
                              hipStream_t stream) {
    const float* x    = (const float*)d_in[0];
    const float* W_ih = (const float*)d_in[1];
    const float* W_hh = (const float*)d_in[2];
    const float* b_ih = (const float*)d_in[3];
    const float* b_hh = (const float*)d_in[4];
    const float* fc_W = (const float*)d_in[5];
    const float* fc_b = (const float*)d_in[6];
    float* out = (float*)d_out;

    dim3 grid(BATCH / ROWS);    // 256 blocks -> 1 per CU
    dim3 block(NTHREADS);       // 4 waves
    hipLaunchKernelGGL(lstm_fused, grid, block, 0, stream,
                       x, W_ih, W_hh, b_ih, b_hh, fc_W, fc_b, out);
}